// Round 2
// baseline (52.075 us; speedup 1.0000x reference)
//
#include <hip/hip_runtime.h>
#include <stdint.h>

// Problem constants (from reference setup_inputs)
#define B_SZ    8
#define N_PTS   4096
#define C_IN    64
#define C_OUT   64
#define KNN     16
#define ROWS    (B_SZ * N_PTS)      // 32768
#define ROWS_PER_BLOCK 32

// ---------------------------------------------------------------------------
// Kernel 1: per-point projections.
//   cbuf[r][o]  = sum_c x[r][c] * (W1[o][c] - W2[o][c]) + bias[o]
//   nbuf[r][o]  = sum_c x[r][c] *  W2[o][c]
// where W1[o][c] = weight[o*128 + c], W2[o][c] = weight[o*128 + 64 + c].
// One wave per block; lane == o. Weights live in registers (fully unrolled,
// compile-time indices). x broadcast across lanes via readlane -> SGPR FMA src.
// ---------------------------------------------------------------------------
__global__ __launch_bounds__(64, 2) void proj_kernel(
    const float* __restrict__ x,
    const float* __restrict__ w,
    const float* __restrict__ bias,
    float* __restrict__ cbuf,
    float* __restrict__ nbuf)
{
    const int lane = threadIdx.x;           // output channel o
    const float* wrow = w + lane * (2 * C_IN);

    float wc[C_IN];   // W1 - W2
    float w2[C_IN];   // W2
#pragma unroll
    for (int c = 0; c < C_IN; ++c) {
        float w1v = wrow[c];
        float w2v = wrow[C_IN + c];
        wc[c] = w1v - w2v;
        w2[c] = w2v;
    }
    const float bv = bias[lane];

    const int r0 = blockIdx.x * ROWS_PER_BLOCK;
    for (int i = 0; i < ROWS_PER_BLOCK; ++i) {
        const int r = r0 + i;
        const float xv = x[(size_t)r * C_IN + lane];
        float a1 = bv;
        float a2 = 0.f;
#pragma unroll
        for (int c = 0; c < C_IN; ++c) {
            // broadcast x[r][c] from lane c (compile-time lane index)
            float xc = __int_as_float(
                __builtin_amdgcn_readlane(__float_as_int(xv), c));
            a1 = fmaf(xc, wc[c], a1);
            a2 = fmaf(xc, w2[c], a2);
        }
        cbuf[(size_t)r * C_OUT + lane] = a1;
        nbuf[(size_t)r * C_OUT + lane] = a2;
    }
}

// ---------------------------------------------------------------------------
// Kernel 2: gather + max + relu + transposed store.
//   out[b][o][n] = relu( max_k ( cbuf[b,n][o] + nbuf[b, idx[b,n,k]][o] ) )
// Block: 256 threads = 4 waves; each wave handles 16 n's of a 64-n tile.
// Lane == o during gather (coalesced 256B reads of nbuf rows).
// Transpose through padded LDS tile so the global store is coalesced over n.
// ---------------------------------------------------------------------------
#define TILE_N 64

__global__ __launch_bounds__(256) void gather_max_kernel(
    const float* __restrict__ cbuf,
    const float* __restrict__ nbuf,
    const int* __restrict__ eidx,
    float* __restrict__ out)
{
    __shared__ float tile[TILE_N][C_OUT + 1];   // +1 pad: (nl+o)%32 distinct

    const int t    = threadIdx.x;
    const int lane = t & 63;
    const int g    = t >> 6;                    // wave id 0..3
    const int b    = blockIdx.x >> 6;           // batch 0..7
    const int tn   = blockIdx.x & 63;           // tile within batch
    const int n0   = tn * TILE_N;

    const float* nb = nbuf + (size_t)b * N_PTS * C_OUT;

    for (int i = 0; i < 16; ++i) {
        const int nl = g * 16 + i;
        const int n  = n0 + nl;
        const size_t r = (size_t)b * N_PTS + n;

        const float cv = cbuf[r * C_OUT + lane];
        const int* ep = eidx + r * KNN;

        float m = -1e30f;
#pragma unroll
        for (int k = 0; k < KNN; ++k) {
            const int idx = ep[k] & (N_PTS - 1);  // wave-uniform; mask = safety
            const float v = nb[(size_t)idx * C_OUT + lane];
            m = fmaxf(m, cv + v);
        }
        tile[nl][lane] = fmaxf(m, 0.f);         // relu(max) == max(relu)
    }

    __syncthreads();

    // out[b][o][n0 + nl], coalesced over nl
    float* ob = out + (size_t)b * C_OUT * N_PTS + n0;
    const int nl = lane;
#pragma unroll
    for (int j = 0; j < 16; ++j) {
        const int o = g * 16 + j;
        ob[(size_t)o * N_PTS + nl] = tile[nl][o];
    }
}

// ---------------------------------------------------------------------------
extern "C" void kernel_launch(void* const* d_in, const int* in_sizes, int n_in,
                              void* d_out, int out_size, void* d_ws, size_t ws_size,
                              hipStream_t stream)
{
    const float* x    = (const float*)d_in[0];
    const int*   eidx = (const int*)d_in[1];    // int64 in reference -> int32 here
    const float* w    = (const float*)d_in[2];  // (64, 128)
    const float* bias = (const float*)d_in[3];  // (64,)
    float*       out  = (float*)d_out;          // (8, 64, 64, 64) f32

    float* cbuf = (float*)d_ws;                 // ROWS * 64 floats (8 MiB)
    float* nbuf = cbuf + (size_t)ROWS * C_OUT;  // ROWS * 64 floats (8 MiB)

    proj_kernel<<<ROWS / ROWS_PER_BLOCK, 64, 0, stream>>>(x, w, bias, cbuf, nbuf);
    gather_max_kernel<<<B_SZ * (N_PTS / TILE_N), 256, 0, stream>>>(cbuf, nbuf, eidx, out);
}

// Round 3
// 49.920 us; speedup vs baseline: 1.0432x; 1.0432x over previous
//
#include <hip/hip_runtime.h>
#include <stdint.h>

#define B_SZ    8
#define N_PTS   4096
#define C_IN    64
#define C_OUT   64
#define KNN     16
#define ROWS    (B_SZ * N_PTS)      // 32768

// ---------------------------------------------------------------------------
// Kernel 0: weight prep.  wcT[c][o] = W1[o][c]-W2[o][c],  w2T[c][o] = W2[o][c]
// (transposed so proj's per-lane weight loads are coalesced)
// ---------------------------------------------------------------------------
__global__ void wprep_kernel(const float* __restrict__ w,
                             float* __restrict__ wcT,
                             float* __restrict__ w2T)
{
    const int id = blockIdx.x * 256 + threadIdx.x;   // (c,o)
    if (id < C_IN * C_OUT) {
        const int c = id >> 6, o = id & 63;
        const float w1 = w[o * 128 + c];
        const float w2 = w[o * 128 + 64 + c];
        wcT[c * 64 + o] = w1 - w2;
        w2T[c * 64 + o] = w2;
    }
}

// ---------------------------------------------------------------------------
// Kernel 1: per-point projections (lane == output channel o).
//   cbuf[r][o] = x[r]·(W1[o]-W2[o]) + bias[o]
//   nbuf[r][o] = x[r]·W2[o]
// x row addresses are block-uniform -> compiler scalarizes to s_load and the
// FMA takes the broadcast value as an SGPR operand (no readlane, no LDS).
// Block swizzle: blockIdx&7 == batch -> batch b's cbuf/nbuf produced on XCD b.
// ---------------------------------------------------------------------------
__global__ __launch_bounds__(64, 2) void proj_kernel(
    const float* __restrict__ x,
    const float* __restrict__ wcT,
    const float* __restrict__ w2T,
    const float* __restrict__ bias,
    float* __restrict__ cbuf,
    float* __restrict__ nbuf)
{
    const int lane = threadIdx.x;

    float wc[C_IN], w2[C_IN];
#pragma unroll
    for (int c = 0; c < C_IN; ++c) {       // coalesced 256B loads
        wc[c] = wcT[c * 64 + lane];
        w2[c] = w2T[c * 64 + lane];
    }
    const float bv = bias[lane];

    const int batch = blockIdx.x & 7;
    const int chunk = blockIdx.x >> 3;      // 0..255
    const int r0 = batch * N_PTS + chunk * 16;

    for (int i = 0; i < 16; ++i) {
        const int r = r0 + i;
        const float* xr = x + (size_t)r * C_IN;   // block-uniform base
        float a1 = bv, a2 = 0.f;
#pragma unroll
        for (int c = 0; c < C_IN; ++c) {
            const float xs = xr[c];               // uniform -> s_load
            a1 = fmaf(xs, wc[c], a1);
            a2 = fmaf(xs, w2[c], a2);
        }
        cbuf[(size_t)r * C_OUT + lane] = a1;
        nbuf[(size_t)r * C_OUT + lane] = a2;
    }
}

// ---------------------------------------------------------------------------
// Kernel 2: gather + max + relu + transposed store.
//   out[b][o][n] = relu( cbuf[b,n][o] + max_k nbuf[b, idx[b,n,k]][o] )
// float4 gathers: 16 lanes cover 64 channels, 4 rows per load instr (1KB).
// Same XCD swizzle (blockIdx&7 == batch) -> gathers hit the local L2 where
// proj just wrote this batch's nbuf (1MB/batch + cbuf 1MB < 4MB L2/XCD).
// ---------------------------------------------------------------------------
__global__ __launch_bounds__(256) void gather_max_kernel(
    const float* __restrict__ cbuf,
    const float* __restrict__ nbuf,
    const int* __restrict__ eidx,
    float* __restrict__ out)
{
    __shared__ float tile[64][65];          // pitch 65: conflict-free both phases

    const int t    = threadIdx.x;
    const int lane = t & 63;
    const int g    = t >> 6;                // wave 0..3
    const int b    = blockIdx.x & 7;        // batch == XCD
    const int tn   = blockIdx.x >> 3;       // 0..63
    const int n0   = tn * 64;

    const float* nb  = nbuf + (size_t)b * N_PTS * C_OUT;
    const int    o4  = (lane & 15) * 4;     // channel block
    const int    sub = lane >> 4;           // row within quad

    for (int i = 0; i < 4; ++i) {
        const int rbase = b * N_PTS + n0 + g * 16 + i * 4;
        // 64 consecutive int32: k=0..15 of rows rbase..rbase+3
        int myidx = eidx[(size_t)rbase * KNN + lane] & (N_PTS - 1);

        const int r = rbase + sub;
        const float4 cv = *(const float4*)(cbuf + (size_t)r * C_OUT + o4);

        float4 mx = make_float4(-1e30f, -1e30f, -1e30f, -1e30f);
#pragma unroll
        for (int k = 0; k < KNN; ++k) {
            const int idx = __shfl(myidx, (lane & 48) | k);
            const float4 v = *(const float4*)(nb + (size_t)idx * C_OUT + o4);
            mx.x = fmaxf(mx.x, v.x);
            mx.y = fmaxf(mx.y, v.y);
            mx.z = fmaxf(mx.z, v.z);
            mx.w = fmaxf(mx.w, v.w);
        }

        const int nl = g * 16 + i * 4 + sub;
        tile[nl][o4 + 0] = fmaxf(cv.x + mx.x, 0.f);   // relu(max)==max(relu)
        tile[nl][o4 + 1] = fmaxf(cv.y + mx.y, 0.f);
        tile[nl][o4 + 2] = fmaxf(cv.z + mx.z, 0.f);
        tile[nl][o4 + 3] = fmaxf(cv.w + mx.w, 0.f);
    }

    __syncthreads();

    float* ob = out + (size_t)b * C_OUT * N_PTS + n0;
#pragma unroll
    for (int j = 0; j < 16; ++j) {
        const int o = g * 16 + j;
        ob[(size_t)o * N_PTS + lane] = tile[lane][o];   // coalesced over n
    }
}

// ---------------------------------------------------------------------------
extern "C" void kernel_launch(void* const* d_in, const int* in_sizes, int n_in,
                              void* d_out, int out_size, void* d_ws, size_t ws_size,
                              hipStream_t stream)
{
    const float* x    = (const float*)d_in[0];
    const int*   eidx = (const int*)d_in[1];    // int64 in ref -> int32 here
    const float* w    = (const float*)d_in[2];  // (64, 128)
    const float* bias = (const float*)d_in[3];  // (64,)
    float*       out  = (float*)d_out;          // (8, 64, 64, 64) f32

    float* cbuf = (float*)d_ws;                        // 8 MiB
    float* nbuf = cbuf + (size_t)ROWS * C_OUT;         // 8 MiB
    float* wcT  = nbuf + (size_t)ROWS * C_OUT;         // 16 KiB
    float* w2T  = wcT + C_IN * C_OUT;                  // 16 KiB

    wprep_kernel<<<16, 256, 0, stream>>>(w, wcT, w2T);
    proj_kernel<<<ROWS / 16, 64, 0, stream>>>(x, wcT, w2T, bias, cbuf, nbuf);
    gather_max_kernel<<<B_SZ * (N_PTS / 64), 256, 0, stream>>>(cbuf, nbuf, eidx, out);
}